// Round 1
// baseline (389.328 us; speedup 1.0000x reference)
//
#include <hip/hip_runtime.h>
#include <hip/hip_bf16.h>

typedef unsigned short u16;
typedef __attribute__((ext_vector_type(8))) short short8;
typedef __attribute__((ext_vector_type(4))) float f32x4;

// round-to-nearest-even f32 -> bf16 bits (finite inputs only)
__device__ __forceinline__ u16 f2b(float f) {
    union { float f; unsigned u; } v; v.f = f;
    unsigned r = v.u + 0x7fffu + ((v.u >> 16) & 1u);
    return (u16)(r >> 16);
}

// ---------------------------------------------------------------------------
// transpose + cast fp32 [R][C] -> bf16 [C][R]
// ---------------------------------------------------------------------------
__global__ void transpose_cast(const float* __restrict__ src,
                               u16* __restrict__ dst, int R, int C) {
    __shared__ float tile[32][33];
    const int c0 = blockIdx.x * 32, r0 = blockIdx.y * 32;
    const int tx = threadIdx.x, ty = threadIdx.y;   // block (32,8)
#pragma unroll
    for (int i = ty; i < 32; i += 8)
        tile[i][tx] = src[(size_t)(r0 + i) * C + c0 + tx];
    __syncthreads();
#pragma unroll
    for (int i = ty; i < 32; i += 8)
        dst[(size_t)(c0 + i) * R + r0 + tx] = f2b(tile[tx][i]);
}

// ---------------------------------------------------------------------------
// LayerNorm: fp32 [rows][256] -> bf16 [rows][256]; one wave per row
// ---------------------------------------------------------------------------
__global__ __launch_bounds__(256) void ln_kernel(
    const float* __restrict__ x, const float* __restrict__ g,
    const float* __restrict__ be, u16* __restrict__ out) {
    const int lane = threadIdx.x & 63;
    const size_t row = (size_t)blockIdx.x * 4 + (threadIdx.x >> 6);
    const float4 v = *((const float4*)(x + row * 256) + lane);
    float s  = v.x + v.y + v.z + v.w;
    float s2 = v.x * v.x + v.y * v.y + v.z * v.z + v.w * v.w;
#pragma unroll
    for (int m = 1; m < 64; m <<= 1) {
        s  += __shfl_xor(s, m);
        s2 += __shfl_xor(s2, m);
    }
    const float mean = s * (1.0f / 256.0f);
    const float var  = s2 * (1.0f / 256.0f) - mean * mean;
    const float rstd = rsqrtf(var + 1e-5f);
    const float4 gv = *((const float4*)g + lane);
    const float4 bv = *((const float4*)be + lane);
    ushort4 o;
    o.x = f2b((v.x - mean) * rstd * gv.x + bv.x);
    o.y = f2b((v.y - mean) * rstd * gv.y + bv.y);
    o.z = f2b((v.z - mean) * rstd * gv.z + bv.z);
    o.w = f2b((v.w - mean) * rstd * gv.w + bv.w);
    *((ushort4*)(out + row * 256) + lane) = o;
}

// ---------------------------------------------------------------------------
// Flash attention, Q=K=V=h (bf16), D=256, N=2048. Block: 64 Q-rows, 4 waves.
// LDS: Krm[64][264] row-major, Ktr[256][72] transposed, Pls[4][16][72].
// x_mid = x + softmax(QK^T/16) V  written to xmid (fp32).
// ---------------------------------------------------------------------------
#define ATTN_LDS_BYTES (64*264*2 + 256*72*2 + 4*16*72*2)

__global__ __launch_bounds__(256, 2) void attn_kernel(
    const u16* __restrict__ h, const float* __restrict__ x,
    float* __restrict__ xmid) {
    extern __shared__ char smem[];
    u16* Krm = (u16*)smem;                              // [64][264]
    u16* Ktr = (u16*)(smem + 64*264*2);                 // [256][72]
    u16* Pls = (u16*)(smem + 64*264*2 + 256*72*2);      // [4][16][72]

    const int tid  = threadIdx.x;
    const int w    = tid >> 6;
    const int lane = tid & 63;
    const int grp  = lane >> 4;
    const int l16  = lane & 15;
    const int b    = blockIdx.y;
    const int q0   = blockIdx.x * 64;

    const u16* hb = h + (size_t)b * (2048 * 256);

    // Q fragments (A-operand): row = l16, k-chunks of 32 per kk
    short8 qf[8];
    {
        const u16* qp = hb + (size_t)(q0 + w * 16 + l16) * 256 + grp * 8;
#pragma unroll
        for (int kk = 0; kk < 8; ++kk)
            qf[kk] = *(const short8*)(qp + kk * 32);
    }

    f32x4 oacc[16];
#pragma unroll
    for (int n = 0; n < 16; ++n) oacc[n] = (f32x4){0.f, 0.f, 0.f, 0.f};
    float m_run[4] = {-1e30f, -1e30f, -1e30f, -1e30f};
    float l_run[4] = {0.f, 0.f, 0.f, 0.f};

    const int sr = tid >> 5;          // staging: row-within-8
    const int sc = (tid & 31) * 8;    // staging: col (elements)
    u16* myP = Pls + w * (16 * 72);

    for (int kt = 0; kt < 32; ++kt) {
        __syncthreads();  // previous tile's LDS reads complete
        // --- phase A: global -> Krm (coalesced b128) ---
        const u16* kp = hb + (size_t)(kt * 64) * 256;
#pragma unroll
        for (int it = 0; it < 8; ++it) {
            const int r = it * 8 + sr;
            short8 v = *(const short8*)(kp + (size_t)r * 256 + sc);
            *(short8*)(Krm + r * 264 + sc) = v;
        }
        __syncthreads();
        // --- phase B: Krm -> Ktr transpose (compile-time vector indices) ---
        {
            const int d = tid;  // 0..255 = one Ktr row per thread
#pragma unroll
            for (int it = 0; it < 8; ++it) {
                short8 tv;
#pragma unroll
                for (int e = 0; e < 8; ++e)
                    tv[e] = (short)Krm[(it * 8 + e) * 264 + d];
                *(short8*)(Ktr + d * 72 + it * 8) = tv;
            }
        }
        __syncthreads();

        // --- S = Q K^T (per wave: 16 q-rows x 64 kv) ---
        f32x4 sacc[4];
#pragma unroll
        for (int j = 0; j < 4; ++j) sacc[j] = (f32x4){0.f, 0.f, 0.f, 0.f};
#pragma unroll
        for (int j = 0; j < 4; ++j) {
            const u16* kb = Krm + (j * 16 + l16) * 264 + grp * 8;
#pragma unroll
            for (int kk = 0; kk < 8; ++kk)
                sacc[j] = __builtin_amdgcn_mfma_f32_16x16x32_bf16(
                    qf[kk], *(const short8*)(kb + kk * 32), sacc[j], 0, 0, 0);
        }

        // --- online softmax (per 16-lane group; rows = grp*4 + r) ---
        float sv[4][4];
#pragma unroll
        for (int j = 0; j < 4; ++j)
#pragma unroll
            for (int r = 0; r < 4; ++r) sv[j][r] = sacc[j][r] * 0.0625f;
#pragma unroll
        for (int r = 0; r < 4; ++r) {
            float m = fmaxf(fmaxf(sv[0][r], sv[1][r]), fmaxf(sv[2][r], sv[3][r]));
            m = fmaxf(m, __shfl_xor(m, 1));
            m = fmaxf(m, __shfl_xor(m, 2));
            m = fmaxf(m, __shfl_xor(m, 4));
            m = fmaxf(m, __shfl_xor(m, 8));
            const float mnew  = fmaxf(m_run[r], m);
            const float alpha = __expf(m_run[r] - mnew);
            m_run[r] = mnew;
            float lt = 0.f;
#pragma unroll
            for (int j = 0; j < 4; ++j) {
                const float p = __expf(sv[j][r] - mnew);
                sv[j][r] = p;
                lt += p;
            }
            lt += __shfl_xor(lt, 1);
            lt += __shfl_xor(lt, 2);
            lt += __shfl_xor(lt, 4);
            lt += __shfl_xor(lt, 8);
            l_run[r] = l_run[r] * alpha + lt;
#pragma unroll
            for (int n = 0; n < 16; ++n) oacc[n][r] *= alpha;
#pragma unroll
            for (int j = 0; j < 4; ++j)
                myP[(grp * 4 + r) * 72 + j * 16 + l16] = f2b(sv[j][r]);
        }

        // --- O += P V  (V tile == K tile, read from Ktr) ---
#pragma unroll
        for (int kk2 = 0; kk2 < 2; ++kk2) {
            const short8 ap = *(const short8*)(myP + l16 * 72 + kk2 * 32 + grp * 8);
#pragma unroll
            for (int n = 0; n < 16; ++n) {
                const short8 bv =
                    *(const short8*)(Ktr + (n * 16 + l16) * 72 + kk2 * 32 + grp * 8);
                oacc[n] = __builtin_amdgcn_mfma_f32_16x16x32_bf16(ap, bv, oacc[n], 0, 0, 0);
            }
        }
    }

    // --- epilogue: xmid = x + O / l ---
    const float* xb = x + (size_t)b * (2048 * 256);
    float* ob = xmid + (size_t)b * (2048 * 256);
    float inv[4];
#pragma unroll
    for (int r = 0; r < 4; ++r) inv[r] = 1.0f / l_run[r];
#pragma unroll
    for (int n = 0; n < 16; ++n)
#pragma unroll
        for (int r = 0; r < 4; ++r) {
            const int row = q0 + w * 16 + grp * 4 + r;
            const int col = n * 16 + l16;
            const size_t idx = (size_t)row * 256 + col;
            ob[idx] = xb[idx] + oacc[n][r] * inv[r];
        }
}

// ---------------------------------------------------------------------------
// Fused FFN: out = xmid + relu(h2 @ w1 + b1) @ w2 + b2  (in-place on xmid)
// Block: 64 tokens, 4 waves; loop over 16 hidden chunks of 64.
// LDS: W1c[64][264] (hid-major, d-contig), W2c[256][72] (d-major, hid-contig),
//      A1[4][16][72] per-wave relu activations.
// ---------------------------------------------------------------------------
#define FFN_LDS_BYTES (64*264*2 + 256*72*2 + 4*16*72*2)

__global__ __launch_bounds__(256, 2) void ffn_kernel(
    const u16* __restrict__ h2, const u16* __restrict__ w1t,
    const u16* __restrict__ w2t, const float* __restrict__ b1,
    const float* __restrict__ b2, float* __restrict__ xmid) {
    extern __shared__ char smem[];
    u16* W1c = (u16*)smem;                              // [64][264]
    u16* W2c = (u16*)(smem + 64*264*2);                 // [256][72]
    u16* A1  = (u16*)(smem + 64*264*2 + 256*72*2);      // [4][16][72]

    const int tid  = threadIdx.x;
    const int w    = tid >> 6;
    const int lane = tid & 63;
    const int grp  = lane >> 4;
    const int l16  = lane & 15;
    const int t0   = blockIdx.x * 64;

    // h2 row fragments (A-operand)
    short8 af[8];
    {
        const u16* ap = h2 + (size_t)(t0 + w * 16 + l16) * 256 + grp * 8;
#pragma unroll
        for (int kk = 0; kk < 8; ++kk)
            af[kk] = *(const short8*)(ap + kk * 32);
    }

    f32x4 oacc[16];
#pragma unroll
    for (int n = 0; n < 16; ++n) oacc[n] = (f32x4){0.f, 0.f, 0.f, 0.f};

    const int sr = tid >> 5, sc = (tid & 31) * 8;
    const int dd = tid >> 3, cc = (tid & 7) * 8;
    u16* myA = A1 + w * (16 * 72);

    for (int hc = 0; hc < 16; ++hc) {
        __syncthreads();
        // stage W1c: rows = hidden (chunk of 64), cols = d (256)
#pragma unroll
        for (int it = 0; it < 8; ++it) {
            const int hr = it * 8 + sr;
            *(short8*)(W1c + hr * 264 + sc) =
                *(const short8*)(w1t + (size_t)(hc * 64 + hr) * 256 + sc);
        }
        // stage W2c: rows = d (256), cols = hidden chunk (64)
#pragma unroll
        for (int it = 0; it < 8; ++it) {
            const int d = it * 32 + dd;
            *(short8*)(W2c + d * 72 + cc) =
                *(const short8*)(w2t + (size_t)d * 1024 + hc * 64 + cc);
        }
        __syncthreads();

        // gemm1: s = h2_tile @ w1[:, chunk]
        f32x4 sacc[4];
#pragma unroll
        for (int j = 0; j < 4; ++j) sacc[j] = (f32x4){0.f, 0.f, 0.f, 0.f};
#pragma unroll
        for (int j = 0; j < 4; ++j) {
            const u16* wb = W1c + (j * 16 + l16) * 264 + grp * 8;
#pragma unroll
            for (int kk = 0; kk < 8; ++kk)
                sacc[j] = __builtin_amdgcn_mfma_f32_16x16x32_bf16(
                    af[kk], *(const short8*)(wb + kk * 32), sacc[j], 0, 0, 0);
        }

        // bias + relu -> A1 (bf16)
#pragma unroll
        for (int j = 0; j < 4; ++j) {
            const float bias = b1[hc * 64 + j * 16 + l16];
#pragma unroll
            for (int r = 0; r < 4; ++r) {
                float v = sacc[j][r] + bias;
                v = fmaxf(v, 0.f);
                myA[(grp * 4 + r) * 72 + j * 16 + l16] = f2b(v);
            }
        }

        // gemm2: out += a1 @ w2[chunk, :]
#pragma unroll
        for (int kk2 = 0; kk2 < 2; ++kk2) {
            const short8 ap = *(const short8*)(myA + l16 * 72 + kk2 * 32 + grp * 8);
#pragma unroll
            for (int n = 0; n < 16; ++n) {
                const short8 bv =
                    *(const short8*)(W2c + (n * 16 + l16) * 72 + kk2 * 32 + grp * 8);
                oacc[n] = __builtin_amdgcn_mfma_f32_16x16x32_bf16(ap, bv, oacc[n], 0, 0, 0);
            }
        }
    }

    // epilogue: in-place residual + b2
#pragma unroll
    for (int n = 0; n < 16; ++n) {
        const float bias2 = b2[n * 16 + l16];
#pragma unroll
        for (int r = 0; r < 4; ++r) {
            const int row = t0 + w * 16 + grp * 4 + r;
            const size_t idx = (size_t)row * 256 + n * 16 + l16;
            xmid[idx] = xmid[idx] + oacc[n][r] + bias2;
        }
    }
}

// ---------------------------------------------------------------------------
extern "C" void kernel_launch(void* const* d_in, const int* in_sizes, int n_in,
                              void* d_out, int out_size, void* d_ws, size_t ws_size,
                              hipStream_t stream) {
    (void)in_sizes; (void)n_in; (void)out_size; (void)ws_size;
    const float* x   = (const float*)d_in[0];
    const float* w1  = (const float*)d_in[1];
    const float* b1  = (const float*)d_in[2];
    const float* w2  = (const float*)d_in[3];
    const float* b2  = (const float*)d_in[4];
    const float* g1  = (const float*)d_in[5];
    const float* be1 = (const float*)d_in[6];
    const float* g2  = (const float*)d_in[7];
    const float* be2 = (const float*)d_in[8];
    float* out = (float*)d_out;

    char* ws = (char*)d_ws;
    u16* h   = (u16*)ws;                        // 16384*256 bf16 = 8 MiB
    u16* h2  = (u16*)(ws + 8388608);            // 8 MiB
    u16* w1t = (u16*)(ws + 16777216);           // [1024][256] bf16
    u16* w2t = (u16*)(ws + 17301504);           // [256][1024] bf16

    hipFuncSetAttribute((const void*)attn_kernel,
                        hipFuncAttributeMaxDynamicSharedMemorySize, ATTN_LDS_BYTES);
    hipFuncSetAttribute((const void*)ffn_kernel,
                        hipFuncAttributeMaxDynamicSharedMemorySize, FFN_LDS_BYTES);

    // weight transposes: w1 [256][1024] -> w1t [1024][256]; w2 [1024][256] -> w2t [256][1024]
    transpose_cast<<<dim3(32, 8), dim3(32, 8), 0, stream>>>(w1, w1t, 256, 1024);
    transpose_cast<<<dim3(8, 32), dim3(32, 8), 0, stream>>>(w2, w2t, 1024, 256);

    // sublayer 1
    ln_kernel<<<4096, 256, 0, stream>>>(x, g1, be1, h);
    attn_kernel<<<dim3(32, 8), 256, ATTN_LDS_BYTES, stream>>>(h, x, out);

    // sublayer 2
    ln_kernel<<<4096, 256, 0, stream>>>(out, g2, be2, h2);
    ffn_kernel<<<256, 256, FFN_LDS_BYTES, stream>>>(h2, w1t, w2t, b1, b2, out);
}

// Round 3
// 228.297 us; speedup vs baseline: 1.7054x; 1.7054x over previous
//
#include <hip/hip_runtime.h>
#include <hip/hip_bf16.h>

typedef unsigned short u16;
typedef __attribute__((ext_vector_type(8))) short short8;
typedef __attribute__((ext_vector_type(4))) float f32x4;

typedef unsigned int __attribute__((address_space(1))) as1_u32;
typedef unsigned int __attribute__((address_space(3))) as3_u32;

__device__ __forceinline__ void gload16(const void* g, void* l) {
    __builtin_amdgcn_global_load_lds((const as1_u32*)g, (as3_u32*)l, 16, 0, 0);
}

// round-to-nearest-even f32 -> bf16 bits (finite inputs only)
__device__ __forceinline__ u16 f2b(float f) {
    union { float f; unsigned u; } v; v.f = f;
    unsigned r = v.u + 0x7fffu + ((v.u >> 16) & 1u);
    return (u16)(r >> 16);
}

// ---------------------------------------------------------------------------
// transpose + cast fp32 [R][C] -> bf16 [C][R]
// ---------------------------------------------------------------------------
__global__ void transpose_cast(const float* __restrict__ src,
                               u16* __restrict__ dst, int R, int C) {
    __shared__ float tile[32][33];
    const int c0 = blockIdx.x * 32, r0 = blockIdx.y * 32;
    const int tx = threadIdx.x, ty = threadIdx.y;   // block (32,8)
#pragma unroll
    for (int i = ty; i < 32; i += 8)
        tile[i][tx] = src[(size_t)(r0 + i) * C + c0 + tx];
    __syncthreads();
#pragma unroll
    for (int i = ty; i < 32; i += 8)
        dst[(size_t)(c0 + i) * R + r0 + tx] = f2b(tile[tx][i]);
}

// ---------------------------------------------------------------------------
// bf16 transpose per batch: src [8][2048][256] -> dst [8][256][2048]
// ---------------------------------------------------------------------------
__global__ void transpose_bf16(const u16* __restrict__ src, u16* __restrict__ dst) {
    __shared__ u16 t[32][33];
    const int b = blockIdx.z;
    const int n0 = blockIdx.x * 32, d0 = blockIdx.y * 32;
    const int tx = threadIdx.x, ty = threadIdx.y;   // block (32,8)
    const u16* s = src + (size_t)b * (2048 * 256);
    u16* d = dst + (size_t)b * (2048 * 256);
#pragma unroll
    for (int i = ty; i < 32; i += 8)
        t[i][tx] = s[(size_t)(n0 + i) * 256 + d0 + tx];
    __syncthreads();
#pragma unroll
    for (int i = ty; i < 32; i += 8)
        d[(size_t)(d0 + i) * 2048 + n0 + tx] = t[tx][i];
}

// ---------------------------------------------------------------------------
// LayerNorm: fp32 [rows][256] -> bf16 [rows][256]; one wave per row
// ---------------------------------------------------------------------------
__global__ __launch_bounds__(256) void ln_kernel(
    const float* __restrict__ x, const float* __restrict__ g,
    const float* __restrict__ be, u16* __restrict__ out) {
    const int lane = threadIdx.x & 63;
    const size_t row = (size_t)blockIdx.x * 4 + (threadIdx.x >> 6);
    const float4 v = *((const float4*)(x + row * 256) + lane);
    float s  = v.x + v.y + v.z + v.w;
    float s2 = v.x * v.x + v.y * v.y + v.z * v.z + v.w * v.w;
#pragma unroll
    for (int m = 1; m < 64; m <<= 1) {
        s  += __shfl_xor(s, m);
        s2 += __shfl_xor(s2, m);
    }
    const float mean = s * (1.0f / 256.0f);
    const float var  = s2 * (1.0f / 256.0f) - mean * mean;
    const float rstd = rsqrtf(var + 1e-5f);
    const float4 gv = *((const float4*)g + lane);
    const float4 bv = *((const float4*)be + lane);
    ushort4 o;
    o.x = f2b((v.x - mean) * rstd * gv.x + bv.x);
    o.y = f2b((v.y - mean) * rstd * gv.y + bv.y);
    o.z = f2b((v.z - mean) * rstd * gv.z + bv.z);
    o.w = f2b((v.w - mean) * rstd * gv.w + bv.w);
    *((ushort4*)(out + row * 256) + lane) = o;
}

// ---------------------------------------------------------------------------
// Flash attention, Q=K=V=h (bf16), D=256, N=2048. Block: 64 Q-rows, 4 waves.
// Double-buffered LDS via global_load_lds (16B), XOR-swizzled (T2/rule#21):
//   buf b at smem + b*65536:  Krm [64][512B] linear, then Vtr [256][128B] linear
//   data placement: LDS[L] = src[row(L)][ (L&rowmask) ^ ((row&7)<<4) ]
//   P scratch at smem + 131072: [4 waves][16][72] u16
// ---------------------------------------------------------------------------
#define ATTN_LDS_BYTES (2*65536 + 4*16*72*2)   // 140288

__global__ __launch_bounds__(256) void attn_kernel(
    const u16* __restrict__ h, const u16* __restrict__ hT,
    const float* __restrict__ x, float* __restrict__ xmid) {
    extern __shared__ char smem[];
    const int tid  = threadIdx.x;
    const int w    = tid >> 6;
    const int lane = tid & 63;
    const int grp  = lane >> 4;
    const int l16  = lane & 15;
    const int b    = blockIdx.y;
    const int q0   = blockIdx.x * 64;

    const u16* hb = h + (size_t)b * (2048 * 256);
    const char* hbB = (const char*)hb;
    const char* hTB = (const char*)(hT + (size_t)b * (2048 * 256));
    u16* myP = (u16*)(smem + 131072) + w * (16 * 72);

    // Q fragments (A-operand)
    short8 qf[8];
    {
        const u16* qp = hb + (size_t)(q0 + w * 16 + l16) * 256 + grp * 8;
#pragma unroll
        for (int kk = 0; kk < 8; ++kk) qf[kk] = *(const short8*)(qp + kk * 32);
    }

    f32x4 oacc[16];
#pragma unroll
    for (int n = 0; n < 16; ++n) oacc[n] = (f32x4){0.f, 0.f, 0.f, 0.f};
    float m_run[4] = {-1e30f, -1e30f, -1e30f, -1e30f};
    float l_run[4] = {0.f, 0.f, 0.f, 0.f};

    // lane-constant staging address pieces (pre-swizzled global source)
    const char* gK0 = hbB + ((size_t)(tid >> 5) << 9)
                          + (((tid & 31) ^ (tid >> 5)) << 4);
    const char* gV0 = hTB + ((size_t)(tid >> 3) << 12)
                          + (((tid & 7) ^ ((tid >> 3) & 7)) << 4);

    // prologue: stage tile 0 into buf0
    {
        char* lK = smem + w * 1024;
        char* lV = smem + 32768 + w * 1024;
#pragma unroll
        for (int it = 0; it < 8; ++it) gload16(gK0 + (size_t)it * 4096, lK + it * 4096);
#pragma unroll
        for (int it = 0; it < 8; ++it) gload16(gV0 + (size_t)it * 131072, lV + it * 4096);
    }
    __syncthreads();

    for (int kt = 0; kt < 32; ++kt) {
        const int cur = kt & 1;
        // issue next tile's staging (other buffer; released by last barrier)
        if (kt < 31) {
            char* lK = smem + (cur ^ 1) * 65536 + w * 1024;
            char* lV = smem + (cur ^ 1) * 65536 + 32768 + w * 1024;
            const char* gK = gK0 + (size_t)(kt + 1) * 32768;
            const char* gV = gV0 + (size_t)(kt + 1) * 128;
#pragma unroll
            for (int it = 0; it < 8; ++it) gload16(gK + (size_t)it * 4096, lK + it * 4096);
#pragma unroll
            for (int it = 0; it < 8; ++it) gload16(gV + (size_t)it * 131072, lV + it * 4096);
        }
        const char* KBb = smem + cur * 65536;
        const char* VBb = KBb + 32768;

        // --- S = Q K^T ---
        f32x4 sacc[4];
#pragma unroll
        for (int j = 0; j < 4; ++j) sacc[j] = (f32x4){0.f, 0.f, 0.f, 0.f};
#pragma unroll
        for (int j = 0; j < 4; ++j) {
            const char* rb = KBb + ((j * 16 + l16) << 9);
#pragma unroll
            for (int kk = 0; kk < 8; ++kk) {
                const int c = grp + 4 * kk;
                const int swz = (c & ~7) | ((c ^ l16) & 7);
                sacc[j] = __builtin_amdgcn_mfma_f32_16x16x32_bf16(
                    qf[kk], *(const short8*)(rb + (swz << 4)), sacc[j], 0, 0, 0);
            }
        }

        // --- online softmax (per 16-lane group; rows = grp*4 + r) ---
        float sv[4][4];
#pragma unroll
        for (int j = 0; j < 4; ++j)
#pragma unroll
            for (int r = 0; r < 4; ++r) sv[j][r] = sacc[j][r] * 0.0625f;
#pragma unroll
        for (int r = 0; r < 4; ++r) {
            float m = fmaxf(fmaxf(sv[0][r], sv[1][r]), fmaxf(sv[2][r], sv[3][r]));
            m = fmaxf(m, __shfl_xor(m, 1));
            m = fmaxf(m, __shfl_xor(m, 2));
            m = fmaxf(m, __shfl_xor(m, 4));
            m = fmaxf(m, __shfl_xor(m, 8));
            const float mnew  = fmaxf(m_run[r], m);
            const float alpha = __expf(m_run[r] - mnew);
            m_run[r] = mnew;
            float lt = 0.f;
#pragma unroll
            for (int j = 0; j < 4; ++j) {
                const float p = __expf(sv[j][r] - mnew);
                sv[j][r] = p;
                lt += p;
            }
            lt += __shfl_xor(lt, 1);
            lt += __shfl_xor(lt, 2);
            lt += __shfl_xor(lt, 4);
            lt += __shfl_xor(lt, 8);
            l_run[r] = l_run[r] * alpha + lt;
#pragma unroll
            for (int n = 0; n < 16; ++n) oacc[n][r] *= alpha;
#pragma unroll
            for (int j = 0; j < 4; ++j)
                myP[(grp * 4 + r) * 72 + j * 16 + l16] = f2b(sv[j][r]);
        }

        // --- O += P V  (V^T tile in Vtr) ---
#pragma unroll
        for (int kk2 = 0; kk2 < 2; ++kk2) {
            const short8 pa = *(const short8*)(myP + l16 * 72 + kk2 * 32 + grp * 8);
#pragma unroll
            for (int n = 0; n < 16; ++n) {
                const int cc2 = (4 * kk2 + grp) ^ (l16 & 7);
                oacc[n] = __builtin_amdgcn_mfma_f32_16x16x32_bf16(
                    pa, *(const short8*)(VBb + ((n * 16 + l16) << 7) + (cc2 << 4)),
                    oacc[n], 0, 0, 0);
            }
        }
        __syncthreads();
    }

    // --- epilogue: xmid = x + O / l ---
    const float* xb = x + (size_t)b * (2048 * 256);
    float* ob = xmid + (size_t)b * (2048 * 256);
    float inv[4];
#pragma unroll
    for (int r = 0; r < 4; ++r) inv[r] = 1.0f / l_run[r];
#pragma unroll
    for (int n = 0; n < 16; ++n)
#pragma unroll
        for (int r = 0; r < 4; ++r) {
            const int row = q0 + w * 16 + grp * 4 + r;
            const int col = n * 16 + l16;
            const size_t idx = (size_t)row * 256 + col;
            ob[idx] = xb[idx] + oacc[n][r] * inv[r];
        }
}

// ---------------------------------------------------------------------------
// Fused FFN: out = xmid + relu(h2 @ w1 + b1) @ w2 + b2  (in-place on xmid)
// Same double-buffered 2-phase structure as attn.
//   buf b: W1c [64][512B] linear+swz, W2c [256][128B] linear+swz
// ---------------------------------------------------------------------------
#define FFN_LDS_BYTES (2*65536 + 4*16*72*2)    // 140288

__global__ __launch_bounds__(256) void ffn_kernel(
    const u16* __restrict__ h2, const u16* __restrict__ w1t,
    const u16* __restrict__ w2t, const float* __restrict__ b1,
    const float* __restrict__ b2, float* __restrict__ xmid) {
    extern __shared__ char smem[];
    const int tid  = threadIdx.x;
    const int w    = tid >> 6;
    const int lane = tid & 63;
    const int grp  = lane >> 4;
    const int l16  = lane & 15;
    const int t0   = blockIdx.x * 64;
    u16* myA = (u16*)(smem + 131072) + w * (16 * 72);

    short8 af[8];
    {
        const u16* ap = h2 + (size_t)(t0 + w * 16 + l16) * 256 + grp * 8;
#pragma unroll
        for (int kk = 0; kk < 8; ++kk) af[kk] = *(const short8*)(ap + kk * 32);
    }

    f32x4 oacc[16];
#pragma unroll
    for (int n = 0; n < 16; ++n) oacc[n] = (f32x4){0.f, 0.f, 0.f, 0.f};

    const char* g10 = (const char*)w1t + ((size_t)(tid >> 5) << 9)
                                       + (((tid & 31) ^ (tid >> 5)) << 4);
    const char* g20 = (const char*)w2t + ((size_t)(tid >> 3) << 11)
                                       + (((tid & 7) ^ ((tid >> 3) & 7)) << 4);

    // prologue: stage chunk 0 into buf0
    {
        char* l1 = smem + w * 1024;
        char* l2 = smem + 32768 + w * 1024;
#pragma unroll
        for (int it = 0; it < 8; ++it) gload16(g10 + (size_t)it * 4096, l1 + it * 4096);
#pragma unroll
        for (int it = 0; it < 8; ++it) gload16(g20 + (size_t)it * 65536, l2 + it * 4096);
    }
    __syncthreads();

    for (int hc = 0; hc < 16; ++hc) {
        const int cur = hc & 1;
        if (hc < 15) {
            char* l1 = smem + (cur ^ 1) * 65536 + w * 1024;
            char* l2 = smem + (cur ^ 1) * 65536 + 32768 + w * 1024;
            const char* g1 = g10 + (size_t)(hc + 1) * 32768;
            const char* g2 = g20 + (size_t)(hc + 1) * 128;
#pragma unroll
            for (int it = 0; it < 8; ++it) gload16(g1 + (size_t)it * 4096, l1 + it * 4096);
#pragma unroll
            for (int it = 0; it < 8; ++it) gload16(g2 + (size_t)it * 65536, l2 + it * 4096);
        }
        const char* W1b = smem + cur * 65536;
        const char* W2b = W1b + 32768;

        // gemm1: s = h2_tile @ w1[:, chunk]
        f32x4 sacc[4];
#pragma unroll
        for (int j = 0; j < 4; ++j) sacc[j] = (f32x4){0.f, 0.f, 0.f, 0.f};
#pragma unroll
        for (int j = 0; j < 4; ++j) {
            const char* rb = W1b + ((j * 16 + l16) << 9);
#pragma unroll
            for (int kk = 0; kk < 8; ++kk) {
                const int c = grp + 4 * kk;
                const int swz = (c & ~7) | ((c ^ l16) & 7);
                sacc[j] = __builtin_amdgcn_mfma_f32_16x16x32_bf16(
                    af[kk], *(const short8*)(rb + (swz << 4)), sacc[j], 0, 0, 0);
            }
        }

        // bias + relu -> A1 (bf16)
#pragma unroll
        for (int j = 0; j < 4; ++j) {
            const float bias = b1[hc * 64 + j * 16 + l16];
#pragma unroll
            for (int r = 0; r < 4; ++r) {
                float v = fmaxf(sacc[j][r] + bias, 0.f);
                myA[(grp * 4 + r) * 72 + j * 16 + l16] = f2b(v);
            }
        }

        // gemm2: out += a1 @ w2[chunk, :]
#pragma unroll
        for (int kk2 = 0; kk2 < 2; ++kk2) {
            const short8 pa = *(const short8*)(myA + l16 * 72 + kk2 * 32 + grp * 8);
#pragma unroll
            for (int n = 0; n < 16; ++n) {
                const int cc2 = (4 * kk2 + grp) ^ (l16 & 7);
                oacc[n] = __builtin_amdgcn_mfma_f32_16x16x32_bf16(
                    pa, *(const short8*)(W2b + ((n * 16 + l16) << 7) + (cc2 << 4)),
                    oacc[n], 0, 0, 0);
            }
        }
        __syncthreads();
    }

    // epilogue: in-place residual + b2
#pragma unroll
    for (int n = 0; n < 16; ++n) {
        const float bias2 = b2[n * 16 + l16];
#pragma unroll
        for (int r = 0; r < 4; ++r) {
            const int row = t0 + w * 16 + grp * 4 + r;
            const size_t idx = (size_t)row * 256 + n * 16 + l16;
            xmid[idx] = xmid[idx] + oacc[n][r] + bias2;
        }
    }
}

// ---------------------------------------------------------------------------
extern "C" void kernel_launch(void* const* d_in, const int* in_sizes, int n_in,
                              void* d_out, int out_size, void* d_ws, size_t ws_size,
                              hipStream_t stream) {
    (void)in_sizes; (void)n_in; (void)out_size; (void)ws_size;
    const float* x   = (const float*)d_in[0];
    const float* w1  = (const float*)d_in[1];
    const float* b1  = (const float*)d_in[2];
    const float* w2  = (const float*)d_in[3];
    const float* b2  = (const float*)d_in[4];
    const float* g1  = (const float*)d_in[5];
    const float* be1 = (const float*)d_in[6];
    const float* g2  = (const float*)d_in[7];
    const float* be2 = (const float*)d_in[8];
    float* out = (float*)d_out;

    char* ws = (char*)d_ws;
    u16* h   = (u16*)ws;                        // 8 MiB (LN1 out; later reused as LN2 out)
    u16* hT  = (u16*)(ws + 8388608);            // 8 MiB transposed h
    u16* w1t = (u16*)(ws + 16777216);           // [1024][256] bf16
    u16* w2t = (u16*)(ws + 17301504);           // [256][1024] bf16

    hipFuncSetAttribute((const void*)attn_kernel,
                        hipFuncAttributeMaxDynamicSharedMemorySize, ATTN_LDS_BYTES);
    hipFuncSetAttribute((const void*)ffn_kernel,
                        hipFuncAttributeMaxDynamicSharedMemorySize, FFN_LDS_BYTES);

    // weight transposes
    transpose_cast<<<dim3(32, 8), dim3(32, 8), 0, stream>>>(w1, w1t, 256, 1024);
    transpose_cast<<<dim3(8, 32), dim3(32, 8), 0, stream>>>(w2, w2t, 1024, 256);

    // sublayer 1
    ln_kernel<<<4096, 256, 0, stream>>>(x, g1, be1, h);
    transpose_bf16<<<dim3(64, 8, 8), dim3(32, 8), 0, stream>>>(h, hT);
    attn_kernel<<<dim3(32, 8), 256, ATTN_LDS_BYTES, stream>>>(h, hT, x, out);

    // sublayer 2 (h buffer reused for LN2 output)
    ln_kernel<<<4096, 256, 0, stream>>>(out, g2, be2, h);
    ffn_kernel<<<256, 256, FFN_LDS_BYTES, stream>>>(h, w1t, w2t, b1, b2, out);
}

// Round 4
// 216.896 us; speedup vs baseline: 1.7950x; 1.0526x over previous
//
#include <hip/hip_runtime.h>
#include <hip/hip_bf16.h>

typedef unsigned short u16;
typedef __attribute__((ext_vector_type(8))) short short8;
typedef __attribute__((ext_vector_type(4))) float f32x4;

typedef unsigned int __attribute__((address_space(1))) as1_u32;
typedef unsigned int __attribute__((address_space(3))) as3_u32;

__device__ __forceinline__ void gload16(const void* g, void* l) {
    __builtin_amdgcn_global_load_lds((const as1_u32*)g, (as3_u32*)l, 16, 0, 0);
}

// round-to-nearest-even f32 -> bf16 bits (finite inputs only)
__device__ __forceinline__ u16 f2b(float f) {
    union { float f; unsigned u; } v; v.f = f;
    unsigned r = v.u + 0x7fffu + ((v.u >> 16) & 1u);
    return (u16)(r >> 16);
}

// ---------------------------------------------------------------------------
// transpose + cast fp32 [R][C] -> bf16 [C][R]
// ---------------------------------------------------------------------------
__global__ void transpose_cast(const float* __restrict__ src,
                               u16* __restrict__ dst, int R, int C) {
    __shared__ float tile[32][33];
    const int c0 = blockIdx.x * 32, r0 = blockIdx.y * 32;
    const int tx = threadIdx.x, ty = threadIdx.y;   // block (32,8)
#pragma unroll
    for (int i = ty; i < 32; i += 8)
        tile[i][tx] = src[(size_t)(r0 + i) * C + c0 + tx];
    __syncthreads();
#pragma unroll
    for (int i = ty; i < 32; i += 8)
        dst[(size_t)(c0 + i) * R + r0 + tx] = f2b(tile[tx][i]);
}

// ---------------------------------------------------------------------------
// bf16 transpose per batch: src [8][2048][256] -> dst [8][256][2048]
// ---------------------------------------------------------------------------
__global__ void transpose_bf16(const u16* __restrict__ src, u16* __restrict__ dst) {
    __shared__ u16 t[32][33];
    const int b = blockIdx.z;
    const int n0 = blockIdx.x * 32, d0 = blockIdx.y * 32;
    const int tx = threadIdx.x, ty = threadIdx.y;   // block (32,8)
    const u16* s = src + (size_t)b * (2048 * 256);
    u16* d = dst + (size_t)b * (2048 * 256);
#pragma unroll
    for (int i = ty; i < 32; i += 8)
        t[i][tx] = s[(size_t)(n0 + i) * 256 + d0 + tx];
    __syncthreads();
#pragma unroll
    for (int i = ty; i < 32; i += 8)
        d[(size_t)(d0 + i) * 2048 + n0 + tx] = t[tx][i];
}

// ---------------------------------------------------------------------------
// LayerNorm: fp32 [rows][256] -> bf16 [rows][256]; one wave per row
// ---------------------------------------------------------------------------
__global__ __launch_bounds__(256) void ln_kernel(
    const float* __restrict__ x, const float* __restrict__ g,
    const float* __restrict__ be, u16* __restrict__ out) {
    const int lane = threadIdx.x & 63;
    const size_t row = (size_t)blockIdx.x * 4 + (threadIdx.x >> 6);
    const float4 v = *((const float4*)(x + row * 256) + lane);
    float s  = v.x + v.y + v.z + v.w;
    float s2 = v.x * v.x + v.y * v.y + v.z * v.z + v.w * v.w;
#pragma unroll
    for (int m = 1; m < 64; m <<= 1) {
        s  += __shfl_xor(s, m);
        s2 += __shfl_xor(s2, m);
    }
    const float mean = s * (1.0f / 256.0f);
    const float var  = s2 * (1.0f / 256.0f) - mean * mean;
    const float rstd = rsqrtf(var + 1e-5f);
    const float4 gv = *((const float4*)g + lane);
    const float4 bv = *((const float4*)be + lane);
    ushort4 o;
    o.x = f2b((v.x - mean) * rstd * gv.x + bv.x);
    o.y = f2b((v.y - mean) * rstd * gv.y + bv.y);
    o.z = f2b((v.z - mean) * rstd * gv.z + bv.z);
    o.w = f2b((v.w - mean) * rstd * gv.w + bv.w);
    *((ushort4*)(out + row * 256) + lane) = o;
}

// ---------------------------------------------------------------------------
// Flash attention, Q=K=V=h (bf16), D=256, N=2048.
// Block: 64 Q-rows, 8 waves (512 thr). Wave w: q-subtile (w&3)*16, kv-half w>>2.
// Each wave keeps private (m,l,O) over its kv-comb; LDS merge at end.
// LDS (XOR-swizzled as R1, rule#21 both-sides):
//   buf b @ b*65536: Krm [64 rows][512B], Vtr [256 rows][128B]
//   P @ 131072: [8 waves][16][40] u16 (row stride 80B)
// ---------------------------------------------------------------------------
#define ATTN_LDS_BYTES (2*65536 + 8*16*40*2)   // 141312

__global__ __launch_bounds__(512) void attn_kernel(
    const u16* __restrict__ h, const u16* __restrict__ hT,
    const float* __restrict__ x, float* __restrict__ xmid) {
    extern __shared__ char smem[];
    const int tid  = threadIdx.x;
    const int w    = tid >> 6;
    const int lane = tid & 63;
    const int grp  = lane >> 4;
    const int l16  = lane & 15;
    const int qsub = w & 3;
    const int kh   = w >> 2;       // kv-half 0/1 of each 64-kv tile
    const int b    = blockIdx.y;
    const int q0   = blockIdx.x * 64;

    const u16* hb = h + (size_t)b * (2048 * 256);
    const char* hbB = (const char*)hb;
    const char* hTB = (const char*)(hT + (size_t)b * (2048 * 256));
    u16* myP = (u16*)(smem + 131072) + w * (16 * 40);

    // Q fragments (A-operand): 16 q-rows per wave
    short8 qf[8];
    {
        const u16* qp = hb + (size_t)(q0 + qsub * 16 + l16) * 256 + grp * 8;
#pragma unroll
        for (int kk = 0; kk < 8; ++kk) qf[kk] = *(const short8*)(qp + kk * 32);
    }

    f32x4 oacc[16];
#pragma unroll
    for (int n = 0; n < 16; ++n) oacc[n] = (f32x4){0.f, 0.f, 0.f, 0.f};
    float m_run[4] = {-1e30f, -1e30f, -1e30f, -1e30f};
    float l_run[4] = {0.f, 0.f, 0.f, 0.f};

    // staging source bases (pre-swizzled global source; LDS written linearly)
    const char* gK0 = hbB + ((size_t)(tid >> 5) << 9)
                          + (((tid & 31) ^ ((tid >> 5) & 7)) << 4);
    const char* gV0 = hTB + ((size_t)(tid >> 3) << 12)
                          + (((tid & 7) ^ ((tid >> 3) & 7)) << 4);

    // prologue: stage tile 0 into buf0 (4 K-chunks + 4 V-chunks per thread)
    {
        char* lK = smem + w * 1024;
        char* lV = smem + 32768 + w * 1024;
#pragma unroll
        for (int it = 0; it < 4; ++it) gload16(gK0 + (size_t)it * 8192, lK + it * 8192);
#pragma unroll
        for (int it = 0; it < 4; ++it) gload16(gV0 + (size_t)it * 262144, lV + it * 8192);
    }
    __syncthreads();

    for (int kt = 0; kt < 32; ++kt) {
        const int cur = kt & 1;
        if (kt < 31) {
            char* lK = smem + (cur ^ 1) * 65536 + w * 1024;
            char* lV = smem + (cur ^ 1) * 65536 + 32768 + w * 1024;
            const char* gK = gK0 + (size_t)(kt + 1) * 32768;
            const char* gV = gV0 + (size_t)(kt + 1) * 128;
#pragma unroll
            for (int it = 0; it < 4; ++it) gload16(gK + (size_t)it * 8192, lK + it * 8192);
#pragma unroll
            for (int it = 0; it < 4; ++it) gload16(gV + (size_t)it * 262144, lV + it * 8192);
        }
        const char* KBb = smem + cur * 65536;
        const char* VBb = KBb + 32768;

        // --- S = Q K^T on this wave's 32-kv half ---
        f32x4 sacc[2];
#pragma unroll
        for (int j = 0; j < 2; ++j) sacc[j] = (f32x4){0.f, 0.f, 0.f, 0.f};
#pragma unroll
        for (int j = 0; j < 2; ++j) {
            const char* rb = KBb + ((kh * 32 + j * 16 + l16) << 9);
#pragma unroll
            for (int kk = 0; kk < 8; ++kk) {
                const int c = grp + 4 * kk;
                const int swz = (c & ~7) | ((c ^ l16) & 7);
                sacc[j] = __builtin_amdgcn_mfma_f32_16x16x32_bf16(
                    qf[kk], *(const short8*)(rb + (swz << 4)), sacc[j], 0, 0, 0);
            }
        }

        // --- online softmax slice (rows grp*4+r over 16 lanes) ---
        float sv[2][4];
#pragma unroll
        for (int j = 0; j < 2; ++j)
#pragma unroll
            for (int r = 0; r < 4; ++r) sv[j][r] = sacc[j][r] * 0.0625f;
        float tmax[4];
#pragma unroll
        for (int r = 0; r < 4; ++r) {
            float m = fmaxf(sv[0][r], sv[1][r]);
            m = fmaxf(m, __shfl_xor(m, 1));
            m = fmaxf(m, __shfl_xor(m, 2));
            m = fmaxf(m, __shfl_xor(m, 4));
            m = fmaxf(m, __shfl_xor(m, 8));
            tmax[r] = m;
        }
        // defer-max (T13): only rescale when some row's max grew past THR=8
        const bool need = (tmax[0] > m_run[0] + 8.f) || (tmax[1] > m_run[1] + 8.f) ||
                          (tmax[2] > m_run[2] + 8.f) || (tmax[3] > m_run[3] + 8.f);
        if (__any(need)) {
#pragma unroll
            for (int r = 0; r < 4; ++r) {
                const float mnew  = fmaxf(m_run[r], tmax[r]);
                const float alpha = __expf(m_run[r] - mnew);
                m_run[r] = mnew;
                l_run[r] *= alpha;
#pragma unroll
                for (int n = 0; n < 16; ++n) oacc[n][r] *= alpha;
            }
        }
#pragma unroll
        for (int r = 0; r < 4; ++r) {
            float lt = 0.f;
#pragma unroll
            for (int j = 0; j < 2; ++j) {
                const float p = __expf(sv[j][r] - m_run[r]);
                lt += p;
                myP[(grp * 4 + r) * 40 + j * 16 + l16] = f2b(p);
            }
            lt += __shfl_xor(lt, 1);
            lt += __shfl_xor(lt, 2);
            lt += __shfl_xor(lt, 4);
            lt += __shfl_xor(lt, 8);
            l_run[r] += lt;
        }

        // --- O += P V on this wave's kv-half ---
        {
            const short8 pa = *(const short8*)(myP + l16 * 40 + grp * 8);
            const int cc2 = ((kh << 2) + grp) ^ (l16 & 7);
#pragma unroll
            for (int n = 0; n < 16; ++n) {
                const short8 bv =
                    *(const short8*)(VBb + ((n * 16 + l16) << 7) + (cc2 << 4));
                oacc[n] = __builtin_amdgcn_mfma_f32_16x16x32_bf16(pa, bv, oacc[n], 0, 0, 0);
            }
        }
        __syncthreads();
    }

    // --- merge kv-half partials: pair (w, w+4) share q-rows ---
    const int pair = w & 3;
    if (w >= 4) {
#pragma unroll
        for (int n = 0; n < 16; ++n)
            *(f32x4*)(smem + pair * 16384 + (n * 16 + l16) * 64 + grp * 16) = oacc[n];
        if (l16 == 0) {
            float* mlp = (float*)(smem + 131072 + pair * 128);
#pragma unroll
            for (int r = 0; r < 4; ++r) {
                mlp[(grp * 4 + r) * 2]     = m_run[r];
                mlp[(grp * 4 + r) * 2 + 1] = l_run[r];
            }
        }
    }
    __syncthreads();
    if (w < 4) {
        float c0[4], c1[4];
        {
            const float* mlp = (const float*)(smem + 131072 + w * 128);
#pragma unroll
            for (int r = 0; r < 4; ++r) {
                const float m1 = mlp[(grp * 4 + r) * 2];
                const float l1 = mlp[(grp * 4 + r) * 2 + 1];
                const float M  = fmaxf(m_run[r], m1);
                const float a0 = __expf(m_run[r] - M);
                const float a1 = __expf(m1 - M);
                const float inv = 1.0f / (l_run[r] * a0 + l1 * a1);
                c0[r] = a0 * inv;
                c1[r] = a1 * inv;
            }
        }
        const float* xb = x + (size_t)b * (2048 * 256);
        float* ob = xmid + (size_t)b * (2048 * 256);
#pragma unroll
        for (int n = 0; n < 16; ++n) {
            const f32x4 o1 = *(const f32x4*)(smem + w * 16384 + (n * 16 + l16) * 64 + grp * 16);
#pragma unroll
            for (int r = 0; r < 4; ++r) {
                const int row = q0 + w * 16 + grp * 4 + r;
                const size_t idx = (size_t)row * 256 + n * 16 + l16;
                ob[idx] = xb[idx] + oacc[n][r] * c0[r] + o1[r] * c1[r];
            }
        }
    }
}

// ---------------------------------------------------------------------------
// Fused FFN: out = xmid + relu(h2 @ w1 + b1) @ w2 + b2
// Block: 64 tokens, 8 waves. Wave w: token-sub (w&3)*16, hidden-half w>>2
// of each 64-hidden chunk. Merge = plain sum of pair partials.
// ---------------------------------------------------------------------------
#define FFN_LDS_BYTES (2*65536 + 8*16*40*2)    // 141312

__global__ __launch_bounds__(512) void ffn_kernel(
    const u16* __restrict__ h2, const u16* __restrict__ w1t,
    const u16* __restrict__ w2t, const float* __restrict__ b1,
    const float* __restrict__ b2, float* __restrict__ xmid) {
    extern __shared__ char smem[];
    const int tid  = threadIdx.x;
    const int w    = tid >> 6;
    const int lane = tid & 63;
    const int grp  = lane >> 4;
    const int l16  = lane & 15;
    const int qsub = w & 3;
    const int hh   = w >> 2;       // hidden-half of each 64-chunk
    const int t0   = blockIdx.x * 64;
    u16* myA = (u16*)(smem + 131072) + w * (16 * 40);

    short8 af[8];
    {
        const u16* ap = h2 + (size_t)(t0 + qsub * 16 + l16) * 256 + grp * 8;
#pragma unroll
        for (int kk = 0; kk < 8; ++kk) af[kk] = *(const short8*)(ap + kk * 32);
    }

    f32x4 oacc[16];
#pragma unroll
    for (int n = 0; n < 16; ++n) oacc[n] = (f32x4){0.f, 0.f, 0.f, 0.f};

    const char* g10 = (const char*)w1t + ((size_t)(tid >> 5) << 9)
                                       + (((tid & 31) ^ ((tid >> 5) & 7)) << 4);
    const char* g20 = (const char*)w2t + ((size_t)(tid >> 3) << 11)
                                       + (((tid & 7) ^ ((tid >> 3) & 7)) << 4);

    // prologue: stage chunk 0 into buf0
    {
        char* l1 = smem + w * 1024;
        char* l2 = smem + 32768 + w * 1024;
#pragma unroll
        for (int it = 0; it < 4; ++it) gload16(g10 + (size_t)it * 8192, l1 + it * 8192);
#pragma unroll
        for (int it = 0; it < 4; ++it) gload16(g20 + (size_t)it * 131072, l2 + it * 8192);
    }
    __syncthreads();

    for (int hc = 0; hc < 16; ++hc) {
        const int cur = hc & 1;
        if (hc < 15) {
            char* l1 = smem + (cur ^ 1) * 65536 + w * 1024;
            char* l2 = smem + (cur ^ 1) * 65536 + 32768 + w * 1024;
            const char* g1 = g10 + (size_t)(hc + 1) * 32768;
            const char* g2 = g20 + (size_t)(hc + 1) * 128;
#pragma unroll
            for (int it = 0; it < 4; ++it) gload16(g1 + (size_t)it * 8192, l1 + it * 8192);
#pragma unroll
            for (int it = 0; it < 4; ++it) gload16(g2 + (size_t)it * 131072, l2 + it * 8192);
        }
        const char* W1b = smem + cur * 65536;
        const char* W2b = W1b + 32768;

        // gemm1: s = h2_tile @ w1[:, this wave's 32-hidden slice]
        f32x4 sacc[2];
#pragma unroll
        for (int j = 0; j < 2; ++j) sacc[j] = (f32x4){0.f, 0.f, 0.f, 0.f};
#pragma unroll
        for (int j = 0; j < 2; ++j) {
            const char* rb = W1b + ((hh * 32 + j * 16 + l16) << 9);
#pragma unroll
            for (int kk = 0; kk < 8; ++kk) {
                const int c = grp + 4 * kk;
                const int swz = (c & ~7) | ((c ^ l16) & 7);
                sacc[j] = __builtin_amdgcn_mfma_f32_16x16x32_bf16(
                    af[kk], *(const short8*)(rb + (swz << 4)), sacc[j], 0, 0, 0);
            }
        }

        // bias + relu -> A1 slice (bf16)
#pragma unroll
        for (int j = 0; j < 2; ++j) {
            const float bias = b1[hc * 64 + hh * 32 + j * 16 + l16];
#pragma unroll
            for (int r = 0; r < 4; ++r) {
                const float v = fmaxf(sacc[j][r] + bias, 0.f);
                myA[(grp * 4 + r) * 40 + j * 16 + l16] = f2b(v);
            }
        }

        // gemm2: O += a1 @ w2[this 32-hidden slice, :]
        {
            const short8 pa = *(const short8*)(myA + l16 * 40 + grp * 8);
            const int cc2 = ((hh << 2) + grp) ^ (l16 & 7);
#pragma unroll
            for (int n = 0; n < 16; ++n) {
                const short8 bv =
                    *(const short8*)(W2b + ((n * 16 + l16) << 7) + (cc2 << 4));
                oacc[n] = __builtin_amdgcn_mfma_f32_16x16x32_bf16(pa, bv, oacc[n], 0, 0, 0);
            }
        }
        __syncthreads();
    }

    // merge: pair (w, w+4) sum partials
    const int pair = w & 3;
    if (w >= 4) {
#pragma unroll
        for (int n = 0; n < 16; ++n)
            *(f32x4*)(smem + pair * 16384 + (n * 16 + l16) * 64 + grp * 16) = oacc[n];
    }
    __syncthreads();
    if (w < 4) {
#pragma unroll
        for (int n = 0; n < 16; ++n) {
            const f32x4 o1 = *(const f32x4*)(smem + w * 16384 + (n * 16 + l16) * 64 + grp * 16);
            const float bias2 = b2[n * 16 + l16];
#pragma unroll
            for (int r = 0; r < 4; ++r) {
                const int row = t0 + w * 16 + grp * 4 + r;
                const size_t idx = (size_t)row * 256 + n * 16 + l16;
                xmid[idx] = xmid[idx] + oacc[n][r] + o1[r] + bias2;
            }
        }
    }
}

// ---------------------------------------------------------------------------
extern "C" void kernel_launch(void* const* d_in, const int* in_sizes, int n_in,
                              void* d_out, int out_size, void* d_ws, size_t ws_size,
                              hipStream_t stream) {
    (void)in_sizes; (void)n_in; (void)out_size; (void)ws_size;
    const float* x   = (const float*)d_in[0];
    const float* w1  = (const float*)d_in[1];
    const float* b1  = (const float*)d_in[2];
    const float* w2  = (const float*)d_in[3];
    const float* b2  = (const float*)d_in[4];
    const float* g1  = (const float*)d_in[5];
    const float* be1 = (const float*)d_in[6];
    const float* g2  = (const float*)d_in[7];
    const float* be2 = (const float*)d_in[8];
    float* out = (float*)d_out;

    char* ws = (char*)d_ws;
    u16* h   = (u16*)ws;                        // 8 MiB (LN1 out; later reused as LN2 out)
    u16* hT  = (u16*)(ws + 8388608);            // 8 MiB transposed h
    u16* w1t = (u16*)(ws + 16777216);           // [1024][256] bf16
    u16* w2t = (u16*)(ws + 17301504);           // [256][1024] bf16

    hipFuncSetAttribute((const void*)attn_kernel,
                        hipFuncAttributeMaxDynamicSharedMemorySize, ATTN_LDS_BYTES);
    hipFuncSetAttribute((const void*)ffn_kernel,
                        hipFuncAttributeMaxDynamicSharedMemorySize, FFN_LDS_BYTES);

    // weight transposes
    transpose_cast<<<dim3(32, 8), dim3(32, 8), 0, stream>>>(w1, w1t, 256, 1024);
    transpose_cast<<<dim3(8, 32), dim3(32, 8), 0, stream>>>(w2, w2t, 1024, 256);

    // sublayer 1
    ln_kernel<<<4096, 256, 0, stream>>>(x, g1, be1, h);
    transpose_bf16<<<dim3(64, 8, 8), dim3(32, 8), 0, stream>>>(h, hT);
    attn_kernel<<<dim3(32, 8), 512, ATTN_LDS_BYTES, stream>>>(h, hT, x, out);

    // sublayer 2 (h buffer reused for LN2 output)
    ln_kernel<<<4096, 256, 0, stream>>>(out, g2, be2, h);
    ffn_kernel<<<256, 512, FFN_LDS_BYTES, stream>>>(h, w1t, w2t, b1, b2, out);
}

// Round 5
// 197.974 us; speedup vs baseline: 1.9666x; 1.0956x over previous
//
#include <hip/hip_runtime.h>
#include <hip/hip_bf16.h>

typedef unsigned short u16;
typedef unsigned int u32;
typedef __attribute__((ext_vector_type(8))) short short8;
typedef __attribute__((ext_vector_type(4))) float f32x4;

typedef unsigned int __attribute__((address_space(1))) as1_u32;
typedef unsigned int __attribute__((address_space(3))) as3_u32;

__device__ __forceinline__ void gload16(const void* g, void* l) {
    __builtin_amdgcn_global_load_lds((const as1_u32*)g, (as3_u32*)l, 16, 0, 0);
}

// round-to-nearest-even f32 -> bf16 bits (finite inputs only)
__device__ __forceinline__ u16 f2b(float f) {
    union { float f; unsigned u; } v; v.f = f;
    unsigned r = v.u + 0x7fffu + ((v.u >> 16) & 1u);
    return (u16)(r >> 16);
}

// ---------------------------------------------------------------------------
// transpose + cast fp32 [R][C] -> bf16 [C][R]
// ---------------------------------------------------------------------------
__global__ void transpose_cast(const float* __restrict__ src,
                               u16* __restrict__ dst, int R, int C) {
    __shared__ float tile[32][33];
    const int c0 = blockIdx.x * 32, r0 = blockIdx.y * 32;
    const int tx = threadIdx.x, ty = threadIdx.y;   // block (32,8)
#pragma unroll
    for (int i = ty; i < 32; i += 8)
        tile[i][tx] = src[(size_t)(r0 + i) * C + c0 + tx];
    __syncthreads();
#pragma unroll
    for (int i = ty; i < 32; i += 8)
        dst[(size_t)(c0 + i) * R + r0 + tx] = f2b(tile[tx][i]);
}

// ---------------------------------------------------------------------------
// bf16 transpose per batch: src [8][2048][256] -> dst [8][256][2048]
// ---------------------------------------------------------------------------
__global__ void transpose_bf16(const u16* __restrict__ src, u16* __restrict__ dst) {
    __shared__ u16 t[32][33];
    const int b = blockIdx.z;
    const int n0 = blockIdx.x * 32, d0 = blockIdx.y * 32;
    const int tx = threadIdx.x, ty = threadIdx.y;   // block (32,8)
    const u16* s = src + (size_t)b * (2048 * 256);
    u16* d = dst + (size_t)b * (2048 * 256);
#pragma unroll
    for (int i = ty; i < 32; i += 8)
        t[i][tx] = s[(size_t)(n0 + i) * 256 + d0 + tx];
    __syncthreads();
#pragma unroll
    for (int i = ty; i < 32; i += 8)
        d[(size_t)(d0 + i) * 2048 + n0 + tx] = t[tx][i];
}

// ---------------------------------------------------------------------------
// LayerNorm: fp32 [rows][256] -> bf16 [rows][256]; one wave per row
// ---------------------------------------------------------------------------
__global__ __launch_bounds__(256) void ln_kernel(
    const float* __restrict__ x, const float* __restrict__ g,
    const float* __restrict__ be, u16* __restrict__ out) {
    const int lane = threadIdx.x & 63;
    const size_t row = (size_t)blockIdx.x * 4 + (threadIdx.x >> 6);
    const float4 v = *((const float4*)(x + row * 256) + lane);
    float s  = v.x + v.y + v.z + v.w;
    float s2 = v.x * v.x + v.y * v.y + v.z * v.z + v.w * v.w;
#pragma unroll
    for (int m = 1; m < 64; m <<= 1) {
        s  += __shfl_xor(s, m);
        s2 += __shfl_xor(s2, m);
    }
    const float mean = s * (1.0f / 256.0f);
    const float var  = s2 * (1.0f / 256.0f) - mean * mean;
    const float rstd = rsqrtf(var + 1e-5f);
    const float4 gv = *((const float4*)g + lane);
    const float4 bv = *((const float4*)be + lane);
    ushort4 o;
    o.x = f2b((v.x - mean) * rstd * gv.x + bv.x);
    o.y = f2b((v.y - mean) * rstd * gv.y + bv.y);
    o.z = f2b((v.z - mean) * rstd * gv.z + bv.z);
    o.w = f2b((v.w - mean) * rstd * gv.w + bv.w);
    *((ushort4*)(out + row * 256) + lane) = o;
}

// ---------------------------------------------------------------------------
// Flash attention, Q=K=V=h (bf16), D=256, N=2048.
// Block: 64 Q-rows, 8 waves (512 thr). Wave w: q-subtile (w&3)*16, kv-half w>>2.
// SWAPPED QK^T: S^T = mfma(K_frag, Q_frag) -> lane owns q-col = l16; softmax
// row stats are per-lane scalars (2 shfl per reduce instead of 8x4).
// LDS (XOR-swizzled, rule#21 both-sides):
//   buf b @ b*65536: Krm [64 rows][512B], Vtr [256 rows][128B]
//   P @ 131072: [8 waves][16 q][40 u16]  (row stride 80B)
// ---------------------------------------------------------------------------
#define ATTN_LDS_BYTES (2*65536 + 8*16*40*2)   // 141312

__global__ __launch_bounds__(512) void attn_kernel(
    const u16* __restrict__ h, const u16* __restrict__ hT,
    const float* __restrict__ x, float* __restrict__ xmid) {
    extern __shared__ char smem[];
    const int tid  = threadIdx.x;
    const int w    = tid >> 6;
    const int lane = tid & 63;
    const int grp  = lane >> 4;
    const int l16  = lane & 15;
    const int qsub = w & 3;
    const int kh   = w >> 2;       // kv-half 0/1 of each 64-kv tile
    const int b    = blockIdx.y;
    const int q0   = blockIdx.x * 64;

    const u16* hb = h + (size_t)b * (2048 * 256);
    const char* hbB = (const char*)hb;
    const char* hTB = (const char*)(hT + (size_t)b * (2048 * 256));
    char* myPb = smem + 131072 + w * 1280;

    // Q fragments (B-operand now; layout identical: q-row = l16, k = grp*8+kk*32)
    short8 qf[8];
    {
        const u16* qp = hb + (size_t)(q0 + qsub * 16 + l16) * 256 + grp * 8;
#pragma unroll
        for (int kk = 0; kk < 8; ++kk) qf[kk] = *(const short8*)(qp + kk * 32);
    }

    f32x4 oacc[16];
#pragma unroll
    for (int n = 0; n < 16; ++n) oacc[n] = (f32x4){0.f, 0.f, 0.f, 0.f};
    float m_run = -1e30f;   // per-lane stats for q = l16
    float l_run = 0.f;

    // staging source bases (pre-swizzled global source; LDS written linearly)
    const char* gK0 = hbB + ((size_t)(tid >> 5) << 9)
                          + (((tid & 31) ^ ((tid >> 5) & 7)) << 4);
    const char* gV0 = hTB + ((size_t)(tid >> 3) << 12)
                          + (((tid & 7) ^ ((tid >> 3) & 7)) << 4);

    // prologue: stage tile 0 into buf0
    {
        char* lK = smem + w * 1024;
        char* lV = smem + 32768 + w * 1024;
#pragma unroll
        for (int it = 0; it < 4; ++it) gload16(gK0 + (size_t)it * 8192, lK + it * 8192);
#pragma unroll
        for (int it = 0; it < 4; ++it) gload16(gV0 + (size_t)it * 262144, lV + it * 8192);
    }
    __syncthreads();

    for (int kt = 0; kt < 32; ++kt) {
        const int cur = kt & 1;
        if (kt < 31) {
            char* lK = smem + (cur ^ 1) * 65536 + w * 1024;
            char* lV = smem + (cur ^ 1) * 65536 + 32768 + w * 1024;
            const char* gK = gK0 + (size_t)(kt + 1) * 32768;
            const char* gV = gV0 + (size_t)(kt + 1) * 128;
#pragma unroll
            for (int it = 0; it < 4; ++it) gload16(gK + (size_t)it * 8192, lK + it * 8192);
#pragma unroll
            for (int it = 0; it < 4; ++it) gload16(gV + (size_t)it * 262144, lV + it * 8192);
        }
        const char* KBb = smem + cur * 65536;
        const char* VBb = KBb + 32768;

        // --- S^T = mfma(K_frag, Q_frag): D[kv = grp*4+r (+j*16)][q = l16] ---
        f32x4 sacc[2];
#pragma unroll
        for (int j = 0; j < 2; ++j) sacc[j] = (f32x4){0.f, 0.f, 0.f, 0.f};
#pragma unroll
        for (int j = 0; j < 2; ++j) {
            const char* rb = KBb + ((kh * 32 + j * 16 + l16) << 9);
#pragma unroll
            for (int kk = 0; kk < 8; ++kk) {
                const int c = grp + 4 * kk;
                const int swz = (c & ~7) | ((c ^ l16) & 7);
                sacc[j] = __builtin_amdgcn_mfma_f32_16x16x32_bf16(
                    *(const short8*)(rb + (swz << 4)), qf[kk], sacc[j], 0, 0, 0);
            }
        }

        // --- online softmax: per-lane row q = l16 ---
        float p[2][4];
#pragma unroll
        for (int j = 0; j < 2; ++j)
#pragma unroll
            for (int r = 0; r < 4; ++r) p[j][r] = sacc[j][r] * 0.0625f;
        float m = p[0][0];
#pragma unroll
        for (int j = 0; j < 2; ++j)
#pragma unroll
            for (int r = 0; r < 4; ++r) m = fmaxf(m, p[j][r]);
        m = fmaxf(m, __shfl_xor(m, 16));
        m = fmaxf(m, __shfl_xor(m, 32));
        // defer-max (T13, THR=8)
        if (__any(m > m_run + 8.f)) {
            const float mnew  = fmaxf(m_run, m);
            const float alpha = __expf(m_run - mnew);
            m_run = mnew;
            l_run *= alpha;
            float ar[4];
#pragma unroll
            for (int r = 0; r < 4; ++r) ar[r] = __shfl(alpha, grp * 4 + r);
#pragma unroll
            for (int n = 0; n < 16; ++n)
#pragma unroll
                for (int r = 0; r < 4; ++r) oacc[n][r] *= ar[r];
        }
        float lt = 0.f;
#pragma unroll
        for (int j = 0; j < 2; ++j)
#pragma unroll
            for (int r = 0; r < 4; ++r) {
                p[j][r] = __expf(p[j][r] - m_run);
                lt += p[j][r];
            }
        lt += __shfl_xor(lt, 16);
        lt += __shfl_xor(lt, 32);
        l_run += lt;

        // --- P -> LDS [q = l16][kv]: 4 packed b32 writes ---
#pragma unroll
        for (int j = 0; j < 2; ++j)
#pragma unroll
            for (int rp = 0; rp < 2; ++rp) {
                const u32 pk = (u32)f2b(p[j][rp * 2]) | ((u32)f2b(p[j][rp * 2 + 1]) << 16);
                *(u32*)(myPb + l16 * 80 + (j * 16 + grp * 4 + rp * 2) * 2) = pk;
            }

        // --- O += P V on this wave's kv-half ---
        {
            const short8 pa = *(const short8*)(myPb + l16 * 80 + grp * 16);
            const int cc2 = ((kh << 2) + grp) ^ (l16 & 7);
#pragma unroll
            for (int n = 0; n < 16; ++n) {
                const short8 bv =
                    *(const short8*)(VBb + ((n * 16 + l16) << 7) + (cc2 << 4));
                oacc[n] = __builtin_amdgcn_mfma_f32_16x16x32_bf16(pa, bv, oacc[n], 0, 0, 0);
            }
        }
        __syncthreads();
    }

    // --- merge kv-half partials: pair (w, w+4) share q-rows ---
    const int pair = w & 3;
    if (w >= 4) {
#pragma unroll
        for (int n = 0; n < 16; ++n)
            *(f32x4*)(smem + pair * 16384 + (n * 16 + l16) * 64 + grp * 16) = oacc[n];
        if (lane < 16) {
            float* mlp = (float*)(smem + 131072 + pair * 128);
            mlp[l16 * 2]     = m_run;
            mlp[l16 * 2 + 1] = l_run;
        }
    }
    __syncthreads();
    if (w < 4) {
        float c0[4], c1[4];
        {
            const float* mlp = (const float*)(smem + 131072 + w * 128);
#pragma unroll
            for (int r = 0; r < 4; ++r) {
                const float m0 = __shfl(m_run, grp * 4 + r);
                const float l0 = __shfl(l_run, grp * 4 + r);
                const float m1 = mlp[(grp * 4 + r) * 2];
                const float l1 = mlp[(grp * 4 + r) * 2 + 1];
                const float M  = fmaxf(m0, m1);
                const float a0 = __expf(m0 - M);
                const float a1 = __expf(m1 - M);
                const float inv = 1.0f / (l0 * a0 + l1 * a1);
                c0[r] = a0 * inv;
                c1[r] = a1 * inv;
            }
        }
        const float* xb = x + (size_t)b * (2048 * 256);
        float* ob = xmid + (size_t)b * (2048 * 256);
#pragma unroll
        for (int n = 0; n < 16; ++n) {
            const f32x4 o1 = *(const f32x4*)(smem + w * 16384 + (n * 16 + l16) * 64 + grp * 16);
#pragma unroll
            for (int r = 0; r < 4; ++r) {
                const int row = q0 + w * 16 + grp * 4 + r;
                const size_t idx = (size_t)row * 256 + n * 16 + l16;
                ob[idx] = xb[idx] + oacc[n][r] * c0[r] + o1[r] * c1[r];
            }
        }
    }
}

// ---------------------------------------------------------------------------
// Fused FFN: out = xmid + relu(h2 @ w1 + b1) @ w2 + b2
// Block: 64 tokens, 8 waves. Wave w: token-sub (w&3)*16, hidden-half w>>2.
// SWAPPED gemm1: mfma(W1_frag, h2_frag) -> D[hid = grp*4+r][tok = l16];
// A1 packed b32 writes [tok][hid]; b1 staged in LDS (b128 read per j).
// ---------------------------------------------------------------------------
#define FFN_LDS_BYTES (2*65536 + 8*16*40*2 + 4096)  // 145408

__global__ __launch_bounds__(512) void ffn_kernel(
    const u16* __restrict__ h2, const u16* __restrict__ w1t,
    const u16* __restrict__ w2t, const float* __restrict__ b1,
    const float* __restrict__ b2, float* __restrict__ xmid) {
    extern __shared__ char smem[];
    const int tid  = threadIdx.x;
    const int w    = tid >> 6;
    const int lane = tid & 63;
    const int grp  = lane >> 4;
    const int l16  = lane & 15;
    const int qsub = w & 3;
    const int hh   = w >> 2;       // hidden-half of each 64-chunk
    const int t0   = blockIdx.x * 64;
    char* myAb = smem + 131072 + w * 1280;
    const char* b1lds = smem + 141312;

    short8 af[8];
    {
        const u16* ap = h2 + (size_t)(t0 + qsub * 16 + l16) * 256 + grp * 8;
#pragma unroll
        for (int kk = 0; kk < 8; ++kk) af[kk] = *(const short8*)(ap + kk * 32);
    }

    f32x4 oacc[16];
#pragma unroll
    for (int n = 0; n < 16; ++n) oacc[n] = (f32x4){0.f, 0.f, 0.f, 0.f};

    const char* g10 = (const char*)w1t + ((size_t)(tid >> 5) << 9)
                                       + (((tid & 31) ^ ((tid >> 5) & 7)) << 4);
    const char* g20 = (const char*)w2t + ((size_t)(tid >> 3) << 11)
                                       + (((tid & 7) ^ ((tid >> 3) & 7)) << 4);

    // prologue: stage chunk 0 into buf0 + b1 into LDS
    {
        char* l1 = smem + w * 1024;
        char* l2 = smem + 32768 + w * 1024;
#pragma unroll
        for (int it = 0; it < 4; ++it) gload16(g10 + (size_t)it * 8192, l1 + it * 8192);
#pragma unroll
        for (int it = 0; it < 4; ++it) gload16(g20 + (size_t)it * 131072, l2 + it * 8192);
        if (tid < 256)
            gload16((const char*)b1 + tid * 16, (char*)b1lds + tid * 16);
    }
    __syncthreads();

    for (int hc = 0; hc < 16; ++hc) {
        const int cur = hc & 1;
        if (hc < 15) {
            char* l1 = smem + (cur ^ 1) * 65536 + w * 1024;
            char* l2 = smem + (cur ^ 1) * 65536 + 32768 + w * 1024;
            const char* g1 = g10 + (size_t)(hc + 1) * 32768;
            const char* g2 = g20 + (size_t)(hc + 1) * 128;
#pragma unroll
            for (int it = 0; it < 4; ++it) gload16(g1 + (size_t)it * 8192, l1 + it * 8192);
#pragma unroll
            for (int it = 0; it < 4; ++it) gload16(g2 + (size_t)it * 131072, l2 + it * 8192);
        }
        const char* W1b = smem + cur * 65536;
        const char* W2b = W1b + 32768;

        // gemm1 swapped: D[hid = grp*4+r (+j*16+hh*32)][tok = l16]
        f32x4 sacc[2];
#pragma unroll
        for (int j = 0; j < 2; ++j) sacc[j] = (f32x4){0.f, 0.f, 0.f, 0.f};
#pragma unroll
        for (int j = 0; j < 2; ++j) {
            const char* rb = W1b + ((hh * 32 + j * 16 + l16) << 9);
#pragma unroll
            for (int kk = 0; kk < 8; ++kk) {
                const int c = grp + 4 * kk;
                const int swz = (c & ~7) | ((c ^ l16) & 7);
                sacc[j] = __builtin_amdgcn_mfma_f32_16x16x32_bf16(
                    *(const short8*)(rb + (swz << 4)), af[kk], sacc[j], 0, 0, 0);
            }
        }

        // bias + relu -> A1 [tok = l16][hid], packed b32 writes
#pragma unroll
        for (int j = 0; j < 2; ++j) {
            const f32x4 bj = *(const f32x4*)(b1lds + (hc * 64 + hh * 32 + j * 16 + grp * 4) * 4);
#pragma unroll
            for (int rp = 0; rp < 2; ++rp) {
                const float v0 = fmaxf(sacc[j][rp * 2]     + bj[rp * 2],     0.f);
                const float v1 = fmaxf(sacc[j][rp * 2 + 1] + bj[rp * 2 + 1], 0.f);
                const u32 pk = (u32)f2b(v0) | ((u32)f2b(v1) << 16);
                *(u32*)(myAb + l16 * 80 + (j * 16 + grp * 4 + rp * 2) * 2) = pk;
            }
        }

        // gemm2: O += a1 @ w2[this 32-hidden slice, :]
        {
            const short8 pa = *(const short8*)(myAb + l16 * 80 + grp * 16);
            const int cc2 = ((hh << 2) + grp) ^ (l16 & 7);
#pragma unroll
            for (int n = 0; n < 16; ++n) {
                const short8 bv =
                    *(const short8*)(W2b + ((n * 16 + l16) << 7) + (cc2 << 4));
                oacc[n] = __builtin_amdgcn_mfma_f32_16x16x32_bf16(pa, bv, oacc[n], 0, 0, 0);
            }
        }
        __syncthreads();
    }

    // merge: pair (w, w+4) sum partials
    const int pair = w & 3;
    if (w >= 4) {
#pragma unroll
        for (int n = 0; n < 16; ++n)
            *(f32x4*)(smem + pair * 16384 + (n * 16 + l16) * 64 + grp * 16) = oacc[n];
    }
    __syncthreads();
    if (w < 4) {
#pragma unroll
        for (int n = 0; n < 16; ++n) {
            const f32x4 o1 = *(const f32x4*)(smem + w * 16384 + (n * 16 + l16) * 64 + grp * 16);
            const float bias2 = b2[n * 16 + l16];
#pragma unroll
            for (int r = 0; r < 4; ++r) {
                const int row = t0 + w * 16 + grp * 4 + r;
                const size_t idx = (size_t)row * 256 + n * 16 + l16;
                xmid[idx] = xmid[idx] + oacc[n][r] + o1[r] + bias2;
            }
        }
    }
}

// ---------------------------------------------------------------------------
extern "C" void kernel_launch(void* const* d_in, const int* in_sizes, int n_in,
                              void* d_out, int out_size, void* d_ws, size_t ws_size,
                              hipStream_t stream) {
    (void)in_sizes; (void)n_in; (void)out_size; (void)ws_size;
    const float* x   = (const float*)d_in[0];
    const float* w1  = (const float*)d_in[1];
    const float* b1  = (const float*)d_in[2];
    const float* w2  = (const float*)d_in[3];
    const float* b2  = (const float*)d_in[4];
    const float* g1  = (const float*)d_in[5];
    const float* be1 = (const float*)d_in[6];
    const float* g2  = (const float*)d_in[7];
    const float* be2 = (const float*)d_in[8];
    float* out = (float*)d_out;

    char* ws = (char*)d_ws;
    u16* h   = (u16*)ws;                        // 8 MiB (LN1 out; later reused as LN2 out)
    u16* hT  = (u16*)(ws + 8388608);            // 8 MiB transposed h
    u16* w1t = (u16*)(ws + 16777216);           // [1024][256] bf16
    u16* w2t = (u16*)(ws + 17301504);           // [256][1024] bf16

    hipFuncSetAttribute((const void*)attn_kernel,
                        hipFuncAttributeMaxDynamicSharedMemorySize, ATTN_LDS_BYTES);
    hipFuncSetAttribute((const void*)ffn_kernel,
                        hipFuncAttributeMaxDynamicSharedMemorySize, FFN_LDS_BYTES);

    // weight transposes
    transpose_cast<<<dim3(32, 8), dim3(32, 8), 0, stream>>>(w1, w1t, 256, 1024);
    transpose_cast<<<dim3(8, 32), dim3(32, 8), 0, stream>>>(w2, w2t, 1024, 256);

    // sublayer 1
    ln_kernel<<<4096, 256, 0, stream>>>(x, g1, be1, h);
    transpose_bf16<<<dim3(64, 8, 8), dim3(32, 8), 0, stream>>>(h, hT);
    attn_kernel<<<dim3(32, 8), 512, ATTN_LDS_BYTES, stream>>>(h, hT, x, out);

    // sublayer 2 (h buffer reused for LN2 output)
    ln_kernel<<<4096, 256, 0, stream>>>(out, g2, be2, h);
    ffn_kernel<<<256, 512, FFN_LDS_BYTES, stream>>>(h, w1t, w2t, b1, b2, out);
}